// Round 8
// baseline (275.779 us; speedup 1.0000x reference)
//
#include <hip/hip_runtime.h>

#define N_TOK 2048
#define B_SZ  8
#define E_DIM 256
#define H_DIM 512
#define ITERS (N_TOK / 32)     // 64

typedef __attribute__((ext_vector_type(8))) short bf16x8;
typedef __attribute__((ext_vector_type(4))) float f32x4;
typedef __attribute__((ext_vector_type(4))) unsigned short u16x4;

__device__ __forceinline__ unsigned short f2bf(float f) {
    union { float f; unsigned u; } v; v.f = f;
    unsigned r = v.u + 0x7FFF + ((v.u >> 16) & 1);   // RNE
    return (unsigned short)(r >> 16);
}
__device__ __forceinline__ float bf2f(unsigned short b) {
    union { unsigned u; float f; } v; v.u = ((unsigned)b) << 16;
    return v.f;
}

// ---- Kernel 1: fused prep (vectorized, verified R7) ------------------------
__global__ void prep_kernel(const float* __restrict__ x,
                            const float* __restrict__ hptr,
                            unsigned short* __restrict__ Xn,
                            unsigned short* __restrict__ Vp,
                            float* __restrict__ sumsq) {
    int bid = blockIdx.x;
    int t = threadIdx.x;
    if (bid == 0 && t == 0) *sumsq = 0.0f;
    if (bid < (N_TOK * B_SZ) / 4) {
        // ---- norm path: 4 rows/block, one per wave ----
        int w = t >> 6, lane = t & 63;
        int r = bid * 4 + w;                 // row in x memory order: r = n*B + b
        int n = r >> 3, b = r & 7;
        float4 v = *(const float4*)(x + (size_t)r * E_DIM + lane * 4);
        float s = v.x * v.x + v.y * v.y + v.z * v.z + v.w * v.w;
        #pragma unroll
        for (int o = 32; o > 0; o >>= 1) s += __shfl_xor(s, o);
        float rn = 1.0f / sqrtf(s);
        u16x4 pk;
        pk[0] = f2bf(v.x * rn); pk[1] = f2bf(v.y * rn);
        pk[2] = f2bf(v.z * rn); pk[3] = f2bf(v.w * rn);
        int u = lane >> 1, half = lane & 1;
        *(u16x4*)(Xn + ((size_t)b * N_TOK + n) * E_DIM
                     + (size_t)((u ^ (n & 7)) * 8 + half * 4)) = pk;
    } else {
        // ---- pack-V path (float4 loads) ----
        int lin = bid - (N_TOK * B_SZ) / 4;    // 8192 blocks: (64, 16, 8)
        int jb = lin & 63, hb = (lin >> 6) & 15, b = lin >> 10;
        __shared__ __attribute__((aligned(16))) float tile[32][36];
        int j0 = jb * 32, h0 = hb * 32;
        {
            int j = t >> 3, c = (t & 7) * 4;
            float4 v = *(const float4*)(hptr +
                ((size_t)(j0 + j) * B_SZ + b) * H_DIM + h0 + c);
            *(float4*)(&tile[j][c]) = v;
        }
        __syncthreads();
        size_t base = ((size_t)b * (N_TOK / 32) + jb) * (H_DIM * 32);
        int hcl = t >> 3, jg = (t >> 1) & 3, half = t & 1;
        int hc = h0 + hcl;
        u16x4 pk;
        #pragma unroll
        for (int k = 0; k < 4; k++)
            pk[k] = f2bf(tile[jg * 8 + half * 4 + k][hcl]);
        *(u16x4*)(Vp + base + (size_t)(hc * 4 + (jg ^ ((hcl >> 1) & 3))) * 8
                     + half * 4) = pk;
    }
}

// ---- Kernel 2: fused flash attention, 16-row blocks, slim waves ------------
// ROUND-8: occupancy via SMALLER REAL STATE (not a forced cap — R1/R3/R6
// law). Grid (8, 128) = 1024 blocks, each 16 q-rows x 512 cols x all keys.
// 4 waves: kh = w&1 is the QK key-half (QK duplicated across wave pairs —
// same 8 MFMA/wave as R7, issue is cheap at 17% MfmaUtil); pc = w is the PV
// col-quarter (128 cols): vf[8], O[8] — 64 regs freed vs R7. ~95 arch +
// ~40 acc ~= 135 total -> __launch_bounds__(256,3) (cap 170 > need: no
// spill) -> 3 waves/SIMD = 3 INDEPENDENT blocks/CU (+50% streams).
// Fixed-shift softmax (cos scores in [-1,1]): P = exp(s-1), no max/rescale.
// T5: s_setprio(1) around both MFMA clusters.
#define PT_STRIDE 40   // shorts

__launch_bounds__(256, 3)
__global__ void flash_kernel(const unsigned short* __restrict__ Xn,
                             const unsigned short* __restrict__ Vp,
                             float* __restrict__ out,
                             float* __restrict__ sumsq) {
    __shared__ __attribute__((aligned(16))) unsigned short Kbuf[2][32 * 256];
    __shared__ __attribute__((aligned(16))) unsigned short Pt[16 * PT_STRIDE];
    __shared__ float Lred[2][16];

    int b  = blockIdx.x;           // batch: linear-id % 8 == b -> XCD-pinned
    int q0 = blockIdx.y * 16;
    int t = threadIdx.x;
    int w = t >> 6, lane = t & 63;
    int quad = lane >> 4, nm = lane & 15;
    int kh = w & 1;                // QK key-half (dup across w>>1)
    // pc = w: PV col-quarter

    const unsigned short* Kbase = Xn + (size_t)b * N_TOK * E_DIM;
    const unsigned short* Qrow =
        Xn + ((size_t)b * N_TOK + q0 + nm) * E_DIM;
    const unsigned short* Vtile0 = Vp + (size_t)b * (N_TOK / 32) * (H_DIM * 32);

    // Q fragments (swizzled layout: unit (ec*4+quad) ^ (row&7))
    bf16x8 qf[8];
    #pragma unroll
    for (int ec = 0; ec < 8; ec++)
        qf[ec] = *(const bf16x8*)(Qrow + (size_t)(((ec * 4 + quad) ^ (nm & 7)) * 8));

    f32x4 O[8];
    #pragma unroll
    for (int i = 0; i < 8; i++) O[i] = (f32x4){0.f, 0.f, 0.f, 0.f};
    float l_lane[4];
    #pragma unroll
    for (int r = 0; r < 4; r++) l_lane[r] = 0.0f;

    // K staging: 4 waves cooperatively copy the 16KB tile (swizzle pre-baked)
    auto stage = [&](int tile, int buf) {
        const unsigned short* src0 = Kbase + (size_t)tile * 32 * E_DIM;
        #pragma unroll
        for (int k = 0; k < 4; k++) {
            int chunk = w * 4 + k;                 // 0..15, 1KB each
            __builtin_amdgcn_global_load_lds(
                (const __attribute__((address_space(1))) unsigned int*)
                    (src0 + (size_t)chunk * 512 + lane * 8),
                (__attribute__((address_space(3))) unsigned int*)
                    (&Kbuf[buf][chunk * 512]),
                16, 0, 0);
        }
    };

    stage(0, 0);
    int vswz = (quad ^ ((nm >> 1) & 3)) * 8;
    int krow = kh * 16 + nm;       // the key row this wave computes in QK^T
    int col0 = w * 128;            // this wave's PV column base

    for (int it = 0; it < ITERS; ++it) {
        __syncthreads();                 // drains staging of tile `it`
        int cur = it & 1;

        // ---- V fragment prefetch: this wave's 128-col quarter ----
        const unsigned short* Vt = Vtile0 + (size_t)it * (H_DIM * 32);
        bf16x8 vf[8];
        #pragma unroll
        for (int tt = 0; tt < 8; tt++) {
            int hc = col0 + tt * 16 + nm;
            vf[tt] = *(const bf16x8*)(Vt + (size_t)(hc * 4) * 8 + vswz);
        }

        if (it + 1 < ITERS) stage(it + 1, cur ^ 1);
        const unsigned short* KB = &Kbuf[cur][0];

        // ---- QK^T: 16 q-rows x 16 keys (kh half), K=256, 2 ILP chains ----
        __builtin_amdgcn_s_setprio(1);
        f32x4 sa = (f32x4){0.f,0.f,0.f,0.f}, sb = (f32x4){0.f,0.f,0.f,0.f};
        #pragma unroll
        for (int ec = 0; ec < 4; ec++) {
            int u0 = (((2*ec)   * 4 + quad) ^ (nm & 7)) * 8;
            int u1 = (((2*ec+1) * 4 + quad) ^ (nm & 7)) * 8;
            bf16x8 kf0 = *(const bf16x8*)(KB + krow * 256 + u0);
            bf16x8 kf1 = *(const bf16x8*)(KB + krow * 256 + u1);
            sa = __builtin_amdgcn_mfma_f32_16x16x32_bf16(qf[2*ec],   kf0, sa, 0, 0, 0);
            sb = __builtin_amdgcn_mfma_f32_16x16x32_bf16(qf[2*ec+1], kf1, sb, 0, 0, 0);
        }
        __builtin_amdgcn_s_setprio(0);

        // ---- fixed-shift softmax: P = exp(s-1), publish to shared Pt ----
        // (dup wave pairs write identical values to identical addrs: benign)
        #pragma unroll
        for (int r = 0; r < 4; r++) {
            unsigned short pb = f2bf(__expf((sa[r] + sb[r]) - 1.0f));
            l_lane[r] += bf2f(pb);
            Pt[(quad * 4 + r) * PT_STRIDE + kh * 16 + nm] = pb;
        }

        // raw barrier: waits DS only — staging/V loads stay in flight
        asm volatile("s_waitcnt lgkmcnt(0)" ::: "memory");
        __builtin_amdgcn_s_barrier();
        asm volatile("" ::: "memory");

        bf16x8 pf = *(const bf16x8*)(&Pt[nm * PT_STRIDE + quad * 8]);

        // ---- PV (8 col-tiles x K=32) ----
        __builtin_amdgcn_s_setprio(1);
        #pragma unroll
        for (int tt = 0; tt < 8; tt++)
            O[tt] = __builtin_amdgcn_mfma_f32_16x16x32_bf16(pf, vf[tt], O[tt], 0, 0, 0);
        __builtin_amdgcn_s_setprio(0);
    }

    // ---- epilogue: combine l across key-halves, normalize, write, sumsq ----
    float lv[4];
    #pragma unroll
    for (int r = 0; r < 4; r++) {
        float v = l_lane[r];
        #pragma unroll
        for (int o = 1; o < 16; o <<= 1) v += __shfl_xor(v, o);
        lv[r] = v;                         // sum over this wave's 16 keys
    }
    if (nm == 0) {
        #pragma unroll
        for (int r = 0; r < 4; r++) Lred[kh][quad * 4 + r] = lv[r];
    }
    __syncthreads();
    float linv[4];
    #pragma unroll
    for (int r = 0; r < 4; r++)
        linv[r] = 1.0f / (Lred[0][quad * 4 + r] + Lred[1][quad * 4 + r]);

    float ss = 0.0f;
    #pragma unroll
    for (int tt = 0; tt < 8; tt++) {
        #pragma unroll
        for (int r = 0; r < 4; r++) {
            float val = O[tt][r] * linv[r];
            int row = q0 + quad * 4 + r;
            int col = col0 + tt * 16 + nm;
            out[((size_t)row * B_SZ + b) * H_DIM + col] = val;
            ss += val * val;
        }
    }
    #pragma unroll
    for (int o = 1; o < 64; o <<= 1) ss += __shfl_xor(ss, o);
    if (lane == 0) atomicAdd(sumsq, ss);
}

// ---- Kernel 3: global-norm rescale ----------------------------------------
__global__ void scale_kernel(float* __restrict__ out,
                             const float* __restrict__ sumsq) {
    size_t idx = ((size_t)blockIdx.x * blockDim.x + threadIdx.x) * 4;
    float rs = 1.0f / sqrtf(*sumsq);
    float4 v = *(float4*)(out + idx);
    v.x *= rs; v.y *= rs; v.z *= rs; v.w *= rs;
    *(float4*)(out + idx) = v;
}

extern "C" void kernel_launch(void* const* d_in, const int* in_sizes, int n_in,
                              void* d_out, int out_size, void* d_ws, size_t ws_size,
                              hipStream_t stream) {
    const float* x = (const float*)d_in[0];
    const float* h = (const float*)d_in[1];
    float* out = (float*)d_out;

    unsigned short* Xn = (unsigned short*)d_ws;                  // 8.39 MB
    unsigned short* Vp = Xn + (size_t)B_SZ * N_TOK * E_DIM;      // 16.78 MB
    float* sumsq = (float*)(Vp + (size_t)B_SZ * N_TOK * H_DIM);  // 4 B

    prep_kernel<<<(N_TOK * B_SZ) / 4 + (N_TOK / 32) * (H_DIM / 32) * B_SZ,
                  256, 0, stream>>>(x, h, Xn, Vp, sumsq);
    flash_kernel<<<dim3(B_SZ, N_TOK / 16), 256, 0, stream>>>(Xn, Vp, out, sumsq);
    scale_kernel<<<out_size / (4 * 256), 256, 0, stream>>>(out, sumsq);
}

// Round 9
// 206.205 us; speedup vs baseline: 1.3374x; 1.3374x over previous
//
#include <hip/hip_runtime.h>

#define N_TOK 2048
#define B_SZ  8
#define E_DIM 256
#define H_DIM 512
#define ITERS (N_TOK / 32)     // 64
#define QROWS 64               // q-rows per block (R9: was 32)

typedef __attribute__((ext_vector_type(8))) short bf16x8;
typedef __attribute__((ext_vector_type(4))) float f32x4;
typedef __attribute__((ext_vector_type(4))) unsigned short u16x4;

__device__ __forceinline__ unsigned short f2bf(float f) {
    union { float f; unsigned u; } v; v.f = f;
    unsigned r = v.u + 0x7FFF + ((v.u >> 16) & 1);   // RNE
    return (unsigned short)(r >> 16);
}
__device__ __forceinline__ float bf2f(unsigned short b) {
    union { unsigned u; float f; } v; v.u = ((unsigned)b) << 16;
    return v.f;
}

// ---- Kernel 1: fused prep (vectorized, verified R7) ------------------------
__global__ void prep_kernel(const float* __restrict__ x,
                            const float* __restrict__ hptr,
                            unsigned short* __restrict__ Xn,
                            unsigned short* __restrict__ Vp,
                            float* __restrict__ sumsq) {
    int bid = blockIdx.x;
    int t = threadIdx.x;
    if (bid == 0 && t == 0) *sumsq = 0.0f;
    if (bid < (N_TOK * B_SZ) / 4) {
        // ---- norm path: 4 rows/block, one per wave ----
        int w = t >> 6, lane = t & 63;
        int r = bid * 4 + w;                 // row in x memory order: r = n*B + b
        int n = r >> 3, b = r & 7;
        float4 v = *(const float4*)(x + (size_t)r * E_DIM + lane * 4);
        float s = v.x * v.x + v.y * v.y + v.z * v.z + v.w * v.w;
        #pragma unroll
        for (int o = 32; o > 0; o >>= 1) s += __shfl_xor(s, o);
        float rn = 1.0f / sqrtf(s);
        u16x4 pk;
        pk[0] = f2bf(v.x * rn); pk[1] = f2bf(v.y * rn);
        pk[2] = f2bf(v.z * rn); pk[3] = f2bf(v.w * rn);
        int u = lane >> 1, half = lane & 1;
        *(u16x4*)(Xn + ((size_t)b * N_TOK + n) * E_DIM
                     + (size_t)((u ^ (n & 7)) * 8 + half * 4)) = pk;
    } else {
        // ---- pack-V path (float4 loads) ----
        int lin = bid - (N_TOK * B_SZ) / 4;    // 8192 blocks: (64, 16, 8)
        int jb = lin & 63, hb = (lin >> 6) & 15, b = lin >> 10;
        __shared__ __attribute__((aligned(16))) float tile[32][36];
        int j0 = jb * 32, h0 = hb * 32;
        {
            int j = t >> 3, c = (t & 7) * 4;
            float4 v = *(const float4*)(hptr +
                ((size_t)(j0 + j) * B_SZ + b) * H_DIM + h0 + c);
            *(float4*)(&tile[j][c]) = v;
        }
        __syncthreads();
        size_t base = ((size_t)b * (N_TOK / 32) + jb) * (H_DIM * 32);
        int hcl = t >> 3, jg = (t >> 1) & 3, half = t & 1;
        int hc = h0 + hcl;
        u16x4 pk;
        #pragma unroll
        for (int k = 0; k < 4; k++)
            pk[k] = f2bf(tile[jg * 8 + half * 4 + k][hcl]);
        *(u16x4*)(Vp + base + (size_t)(hc * 4 + (jg ^ ((hcl >> 1) & 3))) * 8
                     + half * 4) = pk;
    }
}

// ---- Kernel 2: fused flash attention, V-dedup 64x256 blocks ----------------
// ROUND-9 theory: the wall is L2 BW on the V stream (R2: -50% LDS/MFMA -> -3%;
// R8: +40% L2 traffic -> +48% time; R7 budget: 2.6GB L2 @ 124us = 60% of L2
// ceiling -> queueing latency). Reshape: 64 rows x 256 cols per block,
// grid (8, 32, 2) (z = H-half; QK duplicated across z — +33% MFMA at 17%
// util = free). Each of 4 waves owns a DISTINCT 64-col slice: vf[4], V bytes
// fetched ONCE per block (16KB/iter, was 64KB -> V L2 2.1GB -> 0.5GB).
// Wave w: QK for row-group w (16 rows) x BOTH key halves (sa/sb chains);
// P published to Pt[w]; after barrier, PV computes ALL 4 row-groups at this
// wave's cols (pf per rg from LDS, O[4][4]).
// ~150 total regs -> no forced cap (R1/R3/R6 law), 2-3 waves/SIMD.
#define PT_STRIDE 40   // shorts

__launch_bounds__(256, 2)
__global__ void flash_kernel(const unsigned short* __restrict__ Xn,
                             const unsigned short* __restrict__ Vp,
                             float* __restrict__ out,
                             float* __restrict__ sumsq) {
    __shared__ __attribute__((aligned(16))) unsigned short Kbuf[2][32 * 256];
    __shared__ __attribute__((aligned(16))) unsigned short Pt[4][16 * PT_STRIDE];
    __shared__ float Lred[4][16];

    int b  = blockIdx.x;           // batch: linear-id % 8 == b -> XCD-pinned
    int q0 = blockIdx.y * QROWS;
    int z  = blockIdx.z;           // h-half
    int t = threadIdx.x;
    int w = t >> 6, lane = t & 63;
    int quad = lane >> 4, nm = lane & 15;
    // w = QK row-group AND PV col-slice (64 cols)

    const unsigned short* Kbase = Xn + (size_t)b * N_TOK * E_DIM;
    const unsigned short* Qrow =
        Xn + ((size_t)b * N_TOK + q0 + w * 16 + nm) * E_DIM;
    const unsigned short* Vtile0 = Vp + (size_t)b * (N_TOK / 32) * (H_DIM * 32);
    int col0 = z * 256 + w * 64;   // this wave's PV column base

    // Q fragments (swizzled layout: unit (ec*4+quad) ^ (row&7))
    bf16x8 qf[8];
    #pragma unroll
    for (int ec = 0; ec < 8; ec++)
        qf[ec] = *(const bf16x8*)(Qrow + (size_t)(((ec * 4 + quad) ^ (nm & 7)) * 8));

    f32x4 O[4][4];                 // [row-group][col-tile]
    #pragma unroll
    for (int i = 0; i < 4; i++)
        #pragma unroll
        for (int j = 0; j < 4; j++) O[i][j] = (f32x4){0.f, 0.f, 0.f, 0.f};
    float l_lane[4];
    #pragma unroll
    for (int r = 0; r < 4; r++) l_lane[r] = 0.0f;

    // K staging: 4 waves cooperatively copy the 16KB tile (swizzle pre-baked)
    auto stage = [&](int tile, int buf) {
        const unsigned short* src0 = Kbase + (size_t)tile * 32 * E_DIM;
        #pragma unroll
        for (int k = 0; k < 4; k++) {
            int chunk = w * 4 + k;                 // 0..15, 1KB each
            __builtin_amdgcn_global_load_lds(
                (const __attribute__((address_space(1))) unsigned int*)
                    (src0 + (size_t)chunk * 512 + lane * 8),
                (__attribute__((address_space(3))) unsigned int*)
                    (&Kbuf[buf][chunk * 512]),
                16, 0, 0);
        }
    };

    stage(0, 0);
    int vswz = (quad ^ ((nm >> 1) & 3)) * 8;

    for (int it = 0; it < ITERS; ++it) {
        __syncthreads();                 // drains staging of tile `it`
        int cur = it & 1;

        // ---- V prefetch: this wave's 64-col slice, read ONCE per block ----
        const unsigned short* Vt = Vtile0 + (size_t)it * (H_DIM * 32);
        bf16x8 vf[4];
        #pragma unroll
        for (int tt = 0; tt < 4; tt++) {
            int hc = col0 + tt * 16 + nm;
            vf[tt] = *(const bf16x8*)(Vt + (size_t)(hc * 4) * 8 + vswz);
        }

        if (it + 1 < ITERS) stage(it + 1, cur ^ 1);
        const unsigned short* KB = &Kbuf[cur][0];

        // ---- QK^T: row-group w (16 rows) x all 32 keys, K=256 ----
        // two 8-deep chains (one per key-half) for ILP
        f32x4 sa = (f32x4){0.f,0.f,0.f,0.f}, sb = (f32x4){0.f,0.f,0.f,0.f};
        #pragma unroll
        for (int ec = 0; ec < 8; ec++) {
            int u = ((ec * 4 + quad) ^ (nm & 7)) * 8;
            bf16x8 kf0 = *(const bf16x8*)(KB + nm * 256 + u);
            bf16x8 kf1 = *(const bf16x8*)(KB + (16 + nm) * 256 + u);
            sa = __builtin_amdgcn_mfma_f32_16x16x32_bf16(qf[ec], kf0, sa, 0, 0, 0);
            sb = __builtin_amdgcn_mfma_f32_16x16x32_bf16(qf[ec], kf1, sb, 0, 0, 0);
        }

        // ---- fixed-shift softmax: P = exp(s-1), publish both key halves ----
        #pragma unroll
        for (int r = 0; r < 4; r++) {
            unsigned short pb0 = f2bf(__expf(sa[r] - 1.0f));
            unsigned short pb1 = f2bf(__expf(sb[r] - 1.0f));
            l_lane[r] += bf2f(pb0) + bf2f(pb1);
            Pt[w][(quad * 4 + r) * PT_STRIDE + nm]      = pb0;
            Pt[w][(quad * 4 + r) * PT_STRIDE + 16 + nm] = pb1;
        }

        // raw barrier: waits DS only — staging/V loads stay in flight
        asm volatile("s_waitcnt lgkmcnt(0)" ::: "memory");
        __builtin_amdgcn_s_barrier();
        asm volatile("" ::: "memory");

        // ---- PV: all 4 row-groups x this wave's 4 col-tiles ----
        #pragma unroll
        for (int rg = 0; rg < 4; rg++) {
            bf16x8 pf = *(const bf16x8*)(&Pt[rg][nm * PT_STRIDE + quad * 8]);
            #pragma unroll
            for (int ct = 0; ct < 4; ct++)
                O[rg][ct] = __builtin_amdgcn_mfma_f32_16x16x32_bf16(
                    pf, vf[ct], O[rg][ct], 0, 0, 0);
        }
    }

    // ---- epilogue: l for own row-group, share via LDS, normalize, write ----
    float lv[4];
    #pragma unroll
    for (int r = 0; r < 4; r++) {
        float v = l_lane[r];
        #pragma unroll
        for (int o = 1; o < 16; o <<= 1) v += __shfl_xor(v, o);
        lv[r] = v;                         // sum over all 32 keys (this iterset)
    }
    if (nm == 0) {
        #pragma unroll
        for (int r = 0; r < 4; r++) Lred[w][quad * 4 + r] = lv[r];
    }
    __syncthreads();

    float ss = 0.0f;
    #pragma unroll
    for (int rg = 0; rg < 4; rg++) {
        float linv[4];
        #pragma unroll
        for (int r = 0; r < 4; r++)
            linv[r] = 1.0f / Lred[rg][quad * 4 + r];
        #pragma unroll
        for (int ct = 0; ct < 4; ct++) {
            #pragma unroll
            for (int r = 0; r < 4; r++) {
                float val = O[rg][ct][r] * linv[r];
                int row = q0 + rg * 16 + quad * 4 + r;
                int col = col0 + ct * 16 + nm;
                out[((size_t)row * B_SZ + b) * H_DIM + col] = val;
                ss += val * val;
            }
        }
    }
    #pragma unroll
    for (int o = 1; o < 64; o <<= 1) ss += __shfl_xor(ss, o);
    if (lane == 0) atomicAdd(sumsq, ss);
}

// ---- Kernel 3: global-norm rescale ----------------------------------------
__global__ void scale_kernel(float* __restrict__ out,
                             const float* __restrict__ sumsq) {
    size_t idx = ((size_t)blockIdx.x * blockDim.x + threadIdx.x) * 4;
    float rs = 1.0f / sqrtf(*sumsq);
    float4 v = *(float4*)(out + idx);
    v.x *= rs; v.y *= rs; v.z *= rs; v.w *= rs;
    *(float4*)(out + idx) = v;
}

extern "C" void kernel_launch(void* const* d_in, const int* in_sizes, int n_in,
                              void* d_out, int out_size, void* d_ws, size_t ws_size,
                              hipStream_t stream) {
    const float* x = (const float*)d_in[0];
    const float* h = (const float*)d_in[1];
    float* out = (float*)d_out;

    unsigned short* Xn = (unsigned short*)d_ws;                  // 8.39 MB
    unsigned short* Vp = Xn + (size_t)B_SZ * N_TOK * E_DIM;      // 16.78 MB
    float* sumsq = (float*)(Vp + (size_t)B_SZ * N_TOK * H_DIM);  // 4 B

    prep_kernel<<<(N_TOK * B_SZ) / 4 + (N_TOK / 32) * (H_DIM / 32) * B_SZ,
                  256, 0, stream>>>(x, h, Xn, Vp, sumsq);
    flash_kernel<<<dim3(B_SZ, N_TOK / QROWS, 2), 256, 0, stream>>>(
        Xn, Vp, out, sumsq);
    scale_kernel<<<out_size / (4 * 256), 256, 0, stream>>>(out, sumsq);
}